// Round 1
// baseline (242.019 us; speedup 1.0000x reference)
//
#include <hip/hip_runtime.h>

// SEIR SDE: B=32768 trajectories, 1000 steps, shared per-step Brownian noise.
// Output layout [step][4][B] float32 (S,E,I,R), 524 MB total -> write-BW bound.
// One thread per trajectory; 64-thread blocks so 512 blocks spread over 256 CUs.

constexpr int   B_TRAJ  = 32768;
constexpr int   NSTEPS  = 1000;
constexpr float DT      = 0.01f;
constexpr float EPS     = 1e-6f;
constexpr float INV_N   = 1.0f / 10000.0f;   // replaces fdiv by N_POP (<=1 ulp, thr is ~2%)

__global__ __launch_bounds__(64, 1) void seir_sde_kernel(
    const float* __restrict__ beta,
    const float* __restrict__ sigma,
    const float* __restrict__ gamma,
    const float* __restrict__ S0,
    const float* __restrict__ E0,
    const float* __restrict__ I0,
    const float* __restrict__ R0,
    const float4* __restrict__ dW,   // [NSTEPS] x (w0,w1,w2,w3) — batch-uniform
    float* __restrict__ out)         // [NSTEPS][4][B_TRAJ]
{
    const int b = blockIdx.x * 64 + threadIdx.x;

    const float bt  = beta[0];
    const float sg  = sigma[0];
    const float gm  = gamma[0];
    const float sdt = sqrtf(DT);     // compile-time folded, correctly rounded (== 0.1f)

    float S = S0[b];
    float E = E0[b];
    float I = I0[b];
    float R = R0[b];

    float* o = out + b;

    for (int s = 0; s < NSTEPS; ++s) {
        // Uniform across lanes -> scalar load path (s_load_dwordx4 from K$).
        const float4 w4 = dW[s];
        const float w0 = w4.x * sdt;
        const float w1 = w4.y * sdt;
        const float w2 = w4.z * sdt;

        // Clamp at step entry (stored values below remain unclamped, matching ref).
        S = fmaxf(S, EPS);
        E = fmaxf(E, EPS);
        I = fmaxf(I, EPS);
        R = fmaxf(R, EPS);

        const float inf_rate = bt * S * I * INV_N;   // beta*S*I/N
        const float exp_rate = sg * E;               // sigma*E
        const float rec_rate = gm * I;               // gamma*I

        // Inputs clamped >= EPS so rates are strictly positive: sqrt is safe.
        const float n_inf = __builtin_amdgcn_sqrtf(inf_rate);
        const float n_exp = __builtin_amdgcn_sqrtf(exp_rate);
        const float n_rec = __builtin_amdgcn_sqrtf(rec_rate);

        const float Sn = S - inf_rate * DT                  - n_inf * w0;
        const float En = E + (inf_rate - exp_rate) * DT     + n_inf * w0 - n_exp * w1;
        const float In = I + (exp_rate - rec_rate) * DT     + n_exp * w1 - n_rec * w2;
        const float Rn = R + rec_rate * DT                  + n_rec * w2;

        // [s][c][b]: four coalesced dword stores (256 B per wave per store).
        o[0 * B_TRAJ] = Sn;
        o[1 * B_TRAJ] = En;
        o[2 * B_TRAJ] = In;
        o[3 * B_TRAJ] = Rn;
        o += 4 * B_TRAJ;

        S = Sn; E = En; I = In; R = Rn;
    }
}

extern "C" void kernel_launch(void* const* d_in, const int* in_sizes, int n_in,
                              void* d_out, int out_size, void* d_ws, size_t ws_size,
                              hipStream_t stream) {
    const float*  beta  = (const float*)d_in[0];
    const float*  sigma = (const float*)d_in[1];
    const float*  gamma = (const float*)d_in[2];
    const float*  S0    = (const float*)d_in[3];
    const float*  E0    = (const float*)d_in[4];
    const float*  I0    = (const float*)d_in[5];
    const float*  R0    = (const float*)d_in[6];
    const float4* dW    = (const float4*)d_in[7];
    float* out = (float*)d_out;

    seir_sde_kernel<<<B_TRAJ / 64, 64, 0, stream>>>(
        beta, sigma, gamma, S0, E0, I0, R0, dW, out);
}

// Round 2
// 115.627 us; speedup vs baseline: 2.0931x; 2.0931x over previous
//
#include <hip/hip_runtime.h>

// SEIR SDE: B=32768 trajectories, 1000 steps, batch-uniform noise.
// Output [step][4][B] f32 = 524 MB -> write-BW floor ~83 us.
// R1 was 242 us = 580 cyc/step: per-iteration vmcnt stall (store-data reg
// hazard) + serial dW load. R2: unroll-4 register rotation for stores,
// LDS-staged pre-scaled dW with 1-step software prefetch, nontemporal stores.

constexpr int   B_TRAJ  = 32768;
constexpr int   NSTEPS  = 1000;
constexpr float DT      = 0.01f;
constexpr float EPS     = 1e-6f;
constexpr float INV_N   = 1.0f / 10000.0f;   // replaces fdiv (<=1 ulp; thr ~2%)

__global__ __launch_bounds__(64) void seir_sde_kernel(
    const float* __restrict__ beta,
    const float* __restrict__ sigma,
    const float* __restrict__ gamma,
    const float* __restrict__ S0,
    const float* __restrict__ E0,
    const float* __restrict__ I0,
    const float* __restrict__ R0,
    const float4* __restrict__ dW,   // [NSTEPS] x (w0,w1,w2,w3)
    float* __restrict__ out)         // [NSTEPS][4][B_TRAJ]
{
    // One-time LDS stage of all noise, pre-scaled by sqrt(dt). 16 KB.
    __shared__ float4 wbuf[NSTEPS + 1];      // +1 dummy so prefetch never branches
    const float sdt = 0.1f;                  // sqrt(0.01), exact
    for (int i = threadIdx.x; i < NSTEPS; i += 64) {
        const float4 w = dW[i];
        wbuf[i] = make_float4(w.x * sdt, w.y * sdt, w.z * sdt, 0.0f);
    }
    if (threadIdx.x == 0) wbuf[NSTEPS] = make_float4(0.f, 0.f, 0.f, 0.f);

    const int b = blockIdx.x * 64 + threadIdx.x;
    const float btn = beta[0] * INV_N;       // hoisted: beta/N
    const float sg  = sigma[0];
    const float gm  = gamma[0];

    float S = S0[b];
    float E = E0[b];
    float I = I0[b];
    float R = R0[b];

    float* o = out + b;

    __syncthreads();

    float4 w = wbuf[0];                      // software pipeline: w for step s
    #pragma unroll 4
    for (int s = 0; s < NSTEPS; ++s) {
        const float4 wn = wbuf[s + 1];       // prefetch next step's noise (LDS)

        // Clamp at step entry; stored values remain unclamped (matches ref).
        S = fmaxf(S, EPS);
        E = fmaxf(E, EPS);
        I = fmaxf(I, EPS);
        R = fmaxf(R, EPS);

        const float inf_rate = btn * S * I;  // beta*S*I/N
        const float exp_rate = sg * E;
        const float rec_rate = gm * I;

        // Rates strictly positive after clamp: raw sqrt is safe.
        const float n_inf = __builtin_amdgcn_sqrtf(inf_rate);
        const float n_exp = __builtin_amdgcn_sqrtf(exp_rate);
        const float n_rec = __builtin_amdgcn_sqrtf(rec_rate);

        const float a_inf = n_inf * w.x;     // already sqrt(dt)-scaled
        const float a_exp = n_exp * w.y;
        const float a_rec = n_rec * w.z;

        const float Sn = S - inf_rate * DT              - a_inf;
        const float En = E + (inf_rate - exp_rate) * DT + a_inf - a_exp;
        const float In = I + (exp_rate - rec_rate) * DT + a_exp - a_rec;
        const float Rn = R + rec_rate * DT              + a_rec;

        // [s][c][b]: 4 coalesced dword stores (256 B/wave each), write-once ->
        // nontemporal hint. Unroll-4 gives the compiler 16 stores of rotation
        // before any vmcnt wait on store-data registers.
        __builtin_nontemporal_store(Sn, o + 0 * B_TRAJ);
        __builtin_nontemporal_store(En, o + 1 * B_TRAJ);
        __builtin_nontemporal_store(In, o + 2 * B_TRAJ);
        __builtin_nontemporal_store(Rn, o + 3 * B_TRAJ);
        o += 4 * B_TRAJ;

        S = Sn; E = En; I = In; R = Rn;
        w = wn;
    }
}

extern "C" void kernel_launch(void* const* d_in, const int* in_sizes, int n_in,
                              void* d_out, int out_size, void* d_ws, size_t ws_size,
                              hipStream_t stream) {
    const float*  beta  = (const float*)d_in[0];
    const float*  sigma = (const float*)d_in[1];
    const float*  gamma = (const float*)d_in[2];
    const float*  S0    = (const float*)d_in[3];
    const float*  E0    = (const float*)d_in[4];
    const float*  I0    = (const float*)d_in[5];
    const float*  R0    = (const float*)d_in[6];
    const float4* dW    = (const float4*)d_in[7];
    float* out = (float*)d_out;

    seir_sde_kernel<<<B_TRAJ / 64, 64, 0, stream>>>(
        beta, sigma, gamma, S0, E0, I0, R0, dW, out);
}

// Round 3
// 112.897 us; speedup vs baseline: 2.1437x; 1.0242x over previous
//
#include <hip/hip_runtime.h>

// SEIR SDE: B=32768 trajectories, 1000 steps, batch-uniform noise.
// Output [step][4][B] f32 = 524 MB -> pure-write floor ~75-83 us.
// R2 = 115.6 us = 277 cyc/step, producer-limited (HBM could drain ~200 cyc/step).
// At 1 wave/SIMD every latency is exposed; the distance-1 LDS prefetch left
// ~60+ cyc of ds_read latency per step on the critical path.
// R3: distance-8 register pipeline for noise (hides ~120cyc LDS latency under
// 8 steps of compute) + unroll-8 (32-deep store register rotation).

constexpr int   B_TRAJ  = 32768;
constexpr int   NSTEPS  = 1000;
constexpr int   PF      = 8;                 // prefetch distance == unroll factor
constexpr float DT      = 0.01f;
constexpr float EPS     = 1e-6f;
constexpr float INV_N   = 1.0f / 10000.0f;   // replaces fdiv (<=1 ulp; thr ~2%)

__global__ __launch_bounds__(64) void seir_sde_kernel(
    const float* __restrict__ beta,
    const float* __restrict__ sigma,
    const float* __restrict__ gamma,
    const float* __restrict__ S0,
    const float* __restrict__ E0,
    const float* __restrict__ I0,
    const float* __restrict__ R0,
    const float4* __restrict__ dW,   // [NSTEPS] x (w0,w1,w2,w3)
    float* __restrict__ out)         // [NSTEPS][4][B_TRAJ]
{
    // One-time LDS stage of all noise, pre-scaled by sqrt(dt). ~16 KB.
    // Padded by PF so the prefetch pipeline never branches.
    __shared__ float4 wbuf[NSTEPS + PF];
    const float sdt = 0.1f;                  // sqrt(0.01), exact
    for (int i = threadIdx.x; i < NSTEPS; i += 64) {
        const float4 w = dW[i];
        wbuf[i] = make_float4(w.x * sdt, w.y * sdt, w.z * sdt, 0.0f);
    }
    for (int i = NSTEPS + threadIdx.x; i < NSTEPS + PF; i += 64)
        wbuf[i] = make_float4(0.f, 0.f, 0.f, 0.f);

    const int b = blockIdx.x * 64 + threadIdx.x;
    const float btn = beta[0] * INV_N;       // hoisted: beta/N
    const float sg  = sigma[0];
    const float gm  = gamma[0];

    float S = S0[b];
    float E = E0[b];
    float I = I0[b];
    float R = R0[b];

    float* o = out + b;

    __syncthreads();

    // Register pipeline: wreg[k] holds noise for step s0+k; all indices are
    // compile-time constants after full unroll (no scratch spill).
    float4 wreg[PF];
    #pragma unroll
    for (int k = 0; k < PF; ++k) wreg[k] = wbuf[k];

    static_assert(NSTEPS % PF == 0, "unroll tail not handled");
    for (int s0 = 0; s0 < NSTEPS; s0 += PF) {
        #pragma unroll
        for (int k = 0; k < PF; ++k) {
            const float4 w = wreg[k];
            // Refill slot k for step s0+k+PF: ds_read has ~8 steps of compute
            // plus stores before its use -> latency fully hidden.
            wreg[k] = wbuf[s0 + k + PF];

            // Clamp at step entry; stored values remain unclamped (matches ref).
            S = fmaxf(S, EPS);
            E = fmaxf(E, EPS);
            I = fmaxf(I, EPS);
            R = fmaxf(R, EPS);

            const float inf_rate = btn * S * I;  // beta*S*I/N
            const float exp_rate = sg * E;
            const float rec_rate = gm * I;

            // Rates strictly positive after clamp: raw sqrt is safe.
            const float n_inf = __builtin_amdgcn_sqrtf(inf_rate);
            const float n_exp = __builtin_amdgcn_sqrtf(exp_rate);
            const float n_rec = __builtin_amdgcn_sqrtf(rec_rate);

            const float a_inf = n_inf * w.x;     // already sqrt(dt)-scaled
            const float a_exp = n_exp * w.y;
            const float a_rec = n_rec * w.z;

            const float Sn = S - inf_rate * DT              - a_inf;
            const float En = E + (inf_rate - exp_rate) * DT + a_inf - a_exp;
            const float In = I + (exp_rate - rec_rate) * DT + a_exp - a_rec;
            const float Rn = R + rec_rate * DT              + a_rec;

            // [s][c][b]: 4 coalesced dword stores (256 B/wave each), write-once.
            __builtin_nontemporal_store(Sn, o + 0 * B_TRAJ);
            __builtin_nontemporal_store(En, o + 1 * B_TRAJ);
            __builtin_nontemporal_store(In, o + 2 * B_TRAJ);
            __builtin_nontemporal_store(Rn, o + 3 * B_TRAJ);
            o += 4 * B_TRAJ;

            S = Sn; E = En; I = In; R = Rn;
        }
    }
}

extern "C" void kernel_launch(void* const* d_in, const int* in_sizes, int n_in,
                              void* d_out, int out_size, void* d_ws, size_t ws_size,
                              hipStream_t stream) {
    const float*  beta  = (const float*)d_in[0];
    const float*  sigma = (const float*)d_in[1];
    const float*  gamma = (const float*)d_in[2];
    const float*  S0    = (const float*)d_in[3];
    const float*  E0    = (const float*)d_in[4];
    const float*  I0    = (const float*)d_in[5];
    const float*  R0    = (const float*)d_in[6];
    const float4* dW    = (const float4*)d_in[7];
    float* out = (float*)d_out;

    seir_sde_kernel<<<B_TRAJ / 64, 64, 0, stream>>>(
        beta, sigma, gamma, S0, E0, I0, R0, dW, out);
}

// Round 5
// 109.937 us; speedup vs baseline: 2.2014x; 1.0269x over previous
//
#include <hip/hip_runtime.h>

// SEIR SDE: B=32768 trajectories, 1000 steps, batch-uniform noise.
// Output [step][4][B] f32 = 524 MB -> pure-write floor ~76-83 us.
// R3 = 112.9 us = 271 cyc/step = chain(~90) + drain(~183) SERIALIZED.
// Theory: in-flight write window too small (unroll-8 x 256B = 8KB/wave) and
// nontemporal stores ack from HBM not L2 -> vmcnt waits expose drain latency.
// R5 (R4 had a bad static_assert: 1000%16!=0): plain stores (L2-ack),
// unroll-20 (up to 63 outstanding stores/wave, ~40KB/CU in flight),
// direct LDS noise reads (R3 proved prefetch depth moot).

constexpr int   B_TRAJ  = 32768;
constexpr int   NSTEPS  = 1000;
constexpr float DT      = 0.01f;
constexpr float EPS     = 1e-6f;
constexpr float INV_N   = 1.0f / 10000.0f;   // replaces fdiv (<=1 ulp; thr ~2%)

__global__ __launch_bounds__(64) void seir_sde_kernel(
    const float* __restrict__ beta,
    const float* __restrict__ sigma,
    const float* __restrict__ gamma,
    const float* __restrict__ S0,
    const float* __restrict__ E0,
    const float* __restrict__ I0,
    const float* __restrict__ R0,
    const float4* __restrict__ dW,   // [NSTEPS] x (w0,w1,w2,w3)
    float* __restrict__ out)         // [NSTEPS][4][B_TRAJ]
{
    // One-time LDS stage of all noise, pre-scaled by sqrt(dt). ~16 KB.
    __shared__ float4 wbuf[NSTEPS];
    const float sdt = 0.1f;                  // sqrt(0.01), exact
    for (int i = threadIdx.x; i < NSTEPS; i += 64) {
        const float4 w = dW[i];
        wbuf[i] = make_float4(w.x * sdt, w.y * sdt, w.z * sdt, 0.0f);
    }

    const int b = blockIdx.x * 64 + threadIdx.x;
    const float btn = beta[0] * INV_N;       // hoisted: beta/N
    const float sg  = sigma[0];
    const float gm  = gamma[0];

    float S = S0[b];
    float E = E0[b];
    float I = I0[b];
    float R = R0[b];

    float* o = out + b;

    __syncthreads();

    // LDS reads (wbuf) cannot alias global stores -> within each unrolled body
    // the compiler hoists ds_reads ahead of the dependent compute.
    static_assert(NSTEPS % 20 == 0, "unroll tail not handled");
    #pragma unroll 20
    for (int s = 0; s < NSTEPS; ++s) {
        const float4 w = wbuf[s];

        // Clamp at step entry; stored values remain unclamped (matches ref).
        S = fmaxf(S, EPS);
        E = fmaxf(E, EPS);
        I = fmaxf(I, EPS);
        R = fmaxf(R, EPS);

        const float inf_rate = btn * S * I;  // beta*S*I/N
        const float exp_rate = sg * E;
        const float rec_rate = gm * I;

        // Rates strictly positive after clamp: raw sqrt is safe.
        const float n_inf = __builtin_amdgcn_sqrtf(inf_rate);
        const float n_exp = __builtin_amdgcn_sqrtf(exp_rate);
        const float n_rec = __builtin_amdgcn_sqrtf(rec_rate);

        const float a_inf = n_inf * w.x;     // already sqrt(dt)-scaled
        const float a_exp = n_exp * w.y;
        const float a_rec = n_rec * w.z;

        const float Sn = S - inf_rate * DT              - a_inf;
        const float En = E + (inf_rate - exp_rate) * DT + a_inf - a_exp;
        const float In = I + (exp_rate - rec_rate) * DT + a_exp - a_rec;
        const float Rn = R + rec_rate * DT              + a_rec;

        // [s][c][b]: 4 coalesced dword stores (256 B/wave each). Plain stores:
        // vmcnt retires on L2 ack; L2 absorbs and drains to HBM asynchronously.
        o[0 * B_TRAJ] = Sn;
        o[1 * B_TRAJ] = En;
        o[2 * B_TRAJ] = In;
        o[3 * B_TRAJ] = Rn;
        o += 4 * B_TRAJ;

        S = Sn; E = En; I = In; R = Rn;
    }
}

extern "C" void kernel_launch(void* const* d_in, const int* in_sizes, int n_in,
                              void* d_out, int out_size, void* d_ws, size_t ws_size,
                              hipStream_t stream) {
    const float*  beta  = (const float*)d_in[0];
    const float*  sigma = (const float*)d_in[1];
    const float*  gamma = (const float*)d_in[2];
    const float*  S0    = (const float*)d_in[3];
    const float*  E0    = (const float*)d_in[4];
    const float*  I0    = (const float*)d_in[5];
    const float*  R0    = (const float*)d_in[6];
    const float4* dW    = (const float4*)d_in[7];
    float* out = (float*)d_out;

    seir_sde_kernel<<<B_TRAJ / 64, 64, 0, stream>>>(
        beta, sigma, gamma, S0, E0, I0, R0, dW, out);
}